// Round 16
// baseline (885.664 us; speedup 1.0000x reference)
//
#include <hip/hip_runtime.h>
#include <hip/hip_bf16.h>
#include <hip/hip_cooperative_groups.h>

namespace cg = cooperative_groups;

#define HID 64
#define HEADS 4

typedef short s16x8 __attribute__((ext_vector_type(8)));   // 8 bf16/f16 (4 VGPRs)
typedef short s16x4 __attribute__((ext_vector_type(4)));
typedef float f32x4 __attribute__((ext_vector_type(4)));
typedef float f32x2 __attribute__((ext_vector_type(2)));

__device__ __forceinline__ float ldw(const void* p, long i, bool f32) {
    return f32 ? ((const float*)p)[i] : (float)((const __hip_bfloat16*)p)[i];
}
__device__ __forceinline__ unsigned short f2b(float f) {   // fp32 -> bf16 (RNE, finite)
    unsigned int u = __builtin_bit_cast(unsigned int, f);
    u += 0x7FFF + ((u >> 16) & 1);
    return (unsigned short)(u >> 16);
}
__device__ __forceinline__ float b2f(unsigned short s) {
    unsigned int u = ((unsigned int)s) << 16;
    return __builtin_bit_cast(float, u);
}
__device__ __forceinline__ short f2h(float f) {
    return __builtin_bit_cast(short, (_Float16)f);
}

#if __has_builtin(__builtin_amdgcn_exp2f)
#define EXP2(x) __builtin_amdgcn_exp2f(x)
#else
#define EXP2(x) exp2f(x)
#endif
#if __has_builtin(__builtin_amdgcn_rcpf)
#define RCP(x) __builtin_amdgcn_rcpf(x)
#else
#define RCP(x) (1.0f / (x))
#endif

// =================== shared device cores (R14-verbatim bodies) ===================

// GEMM: h = A @ W + b. W^T staged in LDS (R14 win), +8 pad -> 2-way conflicts only.
// AMODE 0: A bf16 plane (layer-0 bf16 world, exact). 1: A fp16 plane. 2: hi/lo bf16.
template <int K, int AMODE>
__device__ __forceinline__ void gemm_phase(const unsigned short* __restrict__ Ah,
                                           const unsigned short* __restrict__ Al,
                                           const unsigned short* __restrict__ WtG,
                                           const void* __restrict__ bq, bool f32,
                                           _Float16* __restrict__ h, int M,
                                           unsigned short* Ws, int totalWaves) {
    constexpr int KP = K + 8;
    int tid = threadIdx.x;
    #pragma unroll
    for (int it = 0; it < (64 * K) / 2048; it++) {       // coalesced 16B staging
        int i = it * 2048 + tid * 8;
        int row = i / K, col = i % K;
        *(s16x8*)&Ws[row * KP + col] = *(const s16x8*)(WtG + i);
    }
    __syncthreads();

    int lane = tid & 63, wv = tid >> 6;
    int m16 = lane & 15, quad = lane >> 4;
    float bias[4];
    #pragma unroll
    for (int t = 0; t < 4; t++) bias[t] = ldw(bq, 16 * t + m16, f32);

    int tiles = (M + 15) >> 4;
    for (int tile = blockIdx.x * 4 + wv; tile < tiles; tile += totalWaves) {
        int m0 = tile << 4;
        int row = m0 + m16;
        bool rv = row < M;
        long abase = (long)row * K;
        f32x4 acc[4] = {{0.f,0.f,0.f,0.f},{0.f,0.f,0.f,0.f},{0.f,0.f,0.f,0.f},{0.f,0.f,0.f,0.f}};
        #pragma unroll
        for (int ks = 0; ks < K / 32; ks++) {
            int kb = ks * 32 + quad * 8;
            s16x8 b[4];
            #pragma unroll
            for (int t = 0; t < 4; t++)
                b[t] = *(const s16x8*)&Ws[(16 * t + m16) * KP + kb];
            s16x8 ah = rv ? *(const s16x8*)(Ah + abase + kb) : (s16x8){0,0,0,0,0,0,0,0};
            if (AMODE == 0) {
                #pragma unroll
                for (int t = 0; t < 4; t++)
                    acc[t] = __builtin_amdgcn_mfma_f32_16x16x32_bf16(ah, b[t], acc[t], 0, 0, 0);
            } else if (AMODE == 1) {
                #pragma unroll
                for (int t = 0; t < 4; t++)
                    acc[t] = __builtin_amdgcn_mfma_f32_16x16x32_f16(ah, b[t], acc[t], 0, 0, 0);
            } else {
                #pragma unroll
                for (int t = 0; t < 4; t++)
                    acc[t] = __builtin_amdgcn_mfma_f32_16x16x32_bf16(ah, b[t], acc[t], 0, 0, 0);
                s16x8 al = rv ? *(const s16x8*)(Al + abase + kb) : (s16x8){0,0,0,0,0,0,0,0};
                #pragma unroll
                for (int t = 0; t < 4; t++)
                    acc[t] = __builtin_amdgcn_mfma_f32_16x16x32_bf16(al, b[t], acc[t], 0, 0, 0);
            }
        }
        #pragma unroll
        for (int t = 0; t < 4; t++) {
            #pragma unroll
            for (int r = 0; r < 4; r++) {
                int orow = m0 + quad * 4 + r;    // C/D: col=lane&15, row=quad*4+reg
                if (orow < M) h[(long)orow * 64 + 16 * t + m16] = (_Float16)(acc[t][r] + bias[t]);
            }
        }
    }
}

// Attention: segment softmax (no-max, exp2-folded) + aggregate; fp16 h (L2-fit);
// raw-load depth-8 pipeline (cvt at USE -- R9 lesson); pre-scaled padded ssorted.
__device__ __forceinline__ void attn_phase(const _Float16* __restrict__ h,
    const int* __restrict__ off, const int* __restrict__ ssorted,
    const void* __restrict__ Wl, const void* __restrict__ bl, bool f32,
    unsigned short* __restrict__ xh, unsigned short* __restrict__ xl,
    void* __restrict__ out, int n, int last, int totalWaves) {
    int lane = threadIdx.x & 63;
    int gw = __builtin_amdgcn_readfirstlane(blockIdx.x * 4 + (threadIdx.x >> 6));

    const float LOG2E = 1.44269504f;
    f32x2 w0p[2], w1p[2], bbp[2];
    #pragma unroll
    for (int q = 0; q < 2; q++) {
        #pragma unroll
        for (int c = 0; c < 2; c++) {
            int k = 2 * q + c;
            w0p[q][c] = ldw(Wl, k, f32) * LOG2E;
            w1p[q][c] = ldw(Wl, HEADS + k, f32) * LOG2E;
            bbp[q][c] = ldw(bl, k, f32) * LOG2E;
        }
    }
    const _Float16* hbp = h + lane;

    for (int r = gw; r < n; r += totalWaves) {
        int start = off[r], end = off[r + 1];
        int sv = ssorted[start + lane];              // pad-safe
        float hr = (float)h[(long)r * HID + lane];
        f32x2 cp[2];
        #pragma unroll
        for (int q = 0; q < 2; q++) cp[q] = w1p[q] * hr + bbp[q];
        f32x2 lp[2] = {{0.f, 0.f}, {0.f, 0.f}};
        f32x2 ap[2] = {{0.f, 0.f}, {0.f, 0.f}};

        for (int base = start; base < end; base += 64) {
            if (base != start) sv = ssorted[base + lane];
            int cnt = min(64, end - base);
            #define LD(j) hbp[(long)__builtin_amdgcn_readlane(sv, (j))]
            #define STEP(hc) {                                                 \
                float _h = (float)(hc);                                        \
                _Pragma("unroll")                                              \
                for (int q = 0; q < 2; q++) {                                  \
                    f32x2 t = w0p[q] * _h + cp[q];                             \
                    f32x2 u = t * 0.2f;                                        \
                    t.x = fmaxf(t.x, u.x); t.y = fmaxf(t.y, u.y);              \
                    f32x2 pe; pe.x = EXP2(t.x); pe.y = EXP2(t.y);              \
                    lp[q] += pe;                                               \
                    ap[q] += pe * _h;                                          \
                } }
            _Float16 q0 = LD(0), q1 = LD(1), q2 = LD(2), q3 = LD(3);
            _Float16 q4 = LD(4), q5 = LD(5), q6 = LD(6), q7 = LD(7);
            int j = 0;
            for (; j + 8 <= cnt; j += 8) {
                _Float16 a0 = q0, a1 = q1, a2 = q2, a3 = q3;
                _Float16 a4 = q4, a5 = q5, a6 = q6, a7 = q7;
                if (j + 8 < 64) {
                    q0 = LD(j +  8); q1 = LD(j +  9); q2 = LD(j + 10); q3 = LD(j + 11);
                    q4 = LD(j + 12); q5 = LD(j + 13); q6 = LD(j + 14); q7 = LD(j + 15);
                }
                STEP(a0); STEP(a1); STEP(a2); STEP(a3);
                STEP(a4); STEP(a5); STEP(a6); STEP(a7);
            }
            int remn = cnt - j;
            if (remn > 0) STEP(q0);
            if (remn > 1) STEP(q1);
            if (remn > 2) STEP(q2);
            if (remn > 3) STEP(q3);
            if (remn > 4) STEP(q4);
            if (remn > 5) STEP(q5);
            if (remn > 6) STEP(q6);
            #undef LD
            #undef STEP
        }

        bool has = (end > start);
        if (!last) {
            float v[4];
            #pragma unroll
            for (int k = 0; k < HEADS; k++) {
                float a = has ? ap[k >> 1][k & 1] * RCP(lp[k >> 1][k & 1]) : 0.f;
                v[k] = (a > 0.f) ? a : (__expf(a) - 1.f);
            }
            long o = (long)r * (HID * HEADS) + lane * HEADS;
            if (!f32) {
                s16x4 vf;
                #pragma unroll
                for (int k = 0; k < HEADS; k++) vf[k] = f2h(v[k]);
                *(s16x4*)(xh + o) = vf;
            } else {
                s16x4 vh, vlo;
                #pragma unroll
                for (int k = 0; k < HEADS; k++) {
                    unsigned short hbk = f2b(v[k]);
                    vh[k] = (short)hbk;
                    vlo[k] = (short)f2b(v[k] - b2f(hbk));
                }
                *(s16x4*)(xh + o) = vh;
                *(s16x4*)(xl + o) = vlo;
            }
        } else {
            float s = 0.f;
            #pragma unroll
            for (int k = 0; k < HEADS; k++)
                s += has ? ap[k >> 1][k & 1] * RCP(lp[k >> 1][k & 1]) : 0.f;
            float a = s * 0.25f;
            a = (a > 0.f) ? a : (__expf(a) - 1.f);
            if (f32) ((float*)out)[(long)r * HID + lane] = a;
            else     ((__hip_bfloat16*)out)[(long)r * HID + lane] = (__hip_bfloat16)a;
        }
    }
}

// =================== cooperative mega-kernel (1 dispatch, 10 grid syncs) ==========
__global__ __launch_bounds__(256, 4) void mega(
    const void* nodes, const int* senders, const int* receivers,
    const void* Wq0, const void* bq0, const void* Wl0, const void* bl0,
    const void* Wq1, const void* bq1, const void* Wl1, const void* bl1,
    const void* Wq2, const void* bq2, const void* Wl2, const void* bl2,
    _Float16* h, unsigned short* nh, unsigned short* nl,
    unsigned short* xh, unsigned short* xl,
    unsigned short* T0, unsigned short* T1, unsigned short* T2,
    int* off, int* cnt, int* cursor, int* ssorted, int* bsum,
    void* out, int N, int E) {

    cg::grid_group grid = cg::this_grid();
    __shared__ __align__(16) unsigned short Ws[64 * 264];   // max KP=264
    __shared__ int sscan[256];
    __shared__ int swsum[4];
    __shared__ int sflag;

    int tid = threadIdx.x, bid = blockIdx.x, nb = gridDim.x;
    int g = bid * 256 + tid, stride = nb * 256;
    int totalWaves = nb * 4;
    long nelem = (long)N * 128;

    // ---- phase 0: per-block self-detect + zero cnt + W^T (+ f32 planes) ----
    if (tid == 0) sflag = 0;
    __syncthreads();
    {
        const uint4* pw = (const uint4*)nodes;       // same 32KB window, all blocks
        int hits = 0;
        for (int i = tid; i < 2048; i += 256) {
            uint4 u = pw[i];
            unsigned int w[4] = {u.x, u.y, u.z, u.w};
            #pragma unroll
            for (int j = 0; j < 4; j++) {
                if ((w[j] & 0x7F80u) == 0x7F80u) hits++;
                if (((w[j] >> 16) & 0x7F80u) == 0x7F80u) hits++;
            }
        }
        if (__ballot(hits != 0)) { if ((tid & 63) == 0) sflag = 1; }
    }
    __syncthreads();
    const bool f32 = (sflag != 0);

    for (int i = g; i < N; i += stride) cnt[i] = 0;
    if (f32) {
        for (long i = (long)g * 4; i < nelem; i += (long)stride * 4) {
            f32x4 v = *(const f32x4*)((const float*)nodes + i);
            s16x4 vh, vl;
            #pragma unroll
            for (int j = 0; j < 4; j++) {
                unsigned short hb = f2b(v[j]);
                vh[j] = (short)hb;
                vl[j] = (short)f2b(v[j] - b2f(hb));
            }
            *(s16x4*)(nh + i) = vh;
            *(s16x4*)(nl + i) = vl;
        }
    }
    for (int i = g; i < 40960; i += stride) {
        if (i < 8192) {
            int k = i >> 6, n2 = i & 63;
            T0[n2 * 128 + k] = f32 ? f2b(((const float*)Wq0)[i])
                                   : ((const unsigned short*)Wq0)[i];
        } else {
            const void* W; unsigned short* T; int o;
            if (i < 24576) { W = Wq1; T = T1; o = i - 8192; }
            else           { W = Wq2; T = T2; o = i - 24576; }
            int k = o >> 6, n2 = o & 63;
            float w = ldw(W, o, f32);
            T[n2 * 256 + k] = f32 ? f2b(w) : (unsigned short)f2h(w);
        }
    }
    grid.sync();

    // ---- phase 1: receiver histogram ----
    for (int i = g; i < E; i += stride) atomicAdd(&cnt[receivers[i]], 1);
    grid.sync();

    // ---- phase 2: block-local scan (prefixes persist in LDS) ----
    int CHUNK = (N + nb - 1) / nb;                   // <= 98 for nb >= 256
    int cbase = bid * CHUNK;
    if (tid < CHUNK) sscan[tid] = (cbase + tid < N) ? cnt[cbase + tid] : 0;
    __syncthreads();
    if (tid == 0) {
        int run = 0;
        for (int j = 0; j < CHUNK; j++) { int x = sscan[j]; sscan[j] = run; run += x; }
        bsum[bid] = run;
    }
    grid.sync();

    // ---- phase 3: block 0 exclusive-scans bsum[nb] ----
    if (bid == 0) {
        int W = (nb + 255) / 256;                    // <= 4
        int myv[4]; int mysum = 0;
        for (int j = 0; j < W; j++) {
            int idx = tid * W + j;
            int x = (idx < nb) ? bsum[idx] : 0;
            myv[j] = mysum; mysum += x;
        }
        int lane = tid & 63, wv2 = tid >> 6;
        int incl = mysum;
        #pragma unroll
        for (int s = 1; s < 64; s <<= 1) {
            int t = __shfl_up(incl, s, 64);
            if (lane >= s) incl += t;
        }
        if (lane == 63) swsum[wv2] = incl;
        __syncthreads();
        int woffs = 0;
        for (int i2 = 0; i2 < wv2; i2++) woffs += swsum[i2];
        int texcl = woffs + incl - mysum;
        for (int j = 0; j < W; j++) {
            int idx = tid * W + j;
            if (idx < nb) bsum[idx] = texcl + myv[j];
        }
        if (tid == 255) bsum[nb] = woffs + incl;     // grand total
    }
    grid.sync();

    // ---- phase 4: finalize off/cursor + ssorted pad ----
    if (tid < CHUNK) {
        int idx = cbase + tid;
        if (idx < N) { int v = sscan[tid] + bsum[bid]; off[idx] = v; cursor[idx] = v; }
    }
    if (bid == 0 && tid == 0) off[N] = bsum[nb];
    if (bid == 0 && tid < 64) ssorted[E + tid] = 0;
    grid.sync();

    // ---- phase 5: layer-0 GEMM + edge scatter (pre-scaled sender ids) ----
    if (f32) gemm_phase<128, 2>(nh, nl, T0, bq0, true, h, N, Ws, totalWaves);
    else     gemm_phase<128, 0>((const unsigned short*)nodes, nullptr, T0, bq0,
                                false, h, N, Ws, totalWaves);
    for (int i = g; i < E; i += stride) {
        int pos = atomicAdd(&cursor[receivers[i]], 1);
        ssorted[pos] = senders[i] * HID;
    }
    grid.sync();

    // ---- phase 6: attn layer 0 ----
    attn_phase(h, off, ssorted, Wl0, bl0, f32, xh, xl, nullptr, N, 0, totalWaves);
    grid.sync();

    // ---- phase 7: gemm layer 1 ----
    if (f32) gemm_phase<256, 2>(xh, xl, T1, bq1, true, h, N, Ws, totalWaves);
    else     gemm_phase<256, 1>(xh, nullptr, T1, bq1, false, h, N, Ws, totalWaves);
    grid.sync();

    // ---- phase 8: attn layer 1 ----
    attn_phase(h, off, ssorted, Wl1, bl1, f32, xh, xl, nullptr, N, 0, totalWaves);
    grid.sync();

    // ---- phase 9: gemm layer 2 ----
    if (f32) gemm_phase<256, 2>(xh, xl, T2, bq2, true, h, N, Ws, totalWaves);
    else     gemm_phase<256, 1>(xh, nullptr, T2, bq2, false, h, N, Ws, totalWaves);
    grid.sync();

    // ---- phase 10: attn layer 2 (last: head-mean + elu -> out) ----
    attn_phase(h, off, ssorted, Wl2, bl2, f32, nullptr, nullptr, out, N, 1, totalWaves);
}

// =================== fallback kernels (R14 path, used if coop launch fails) =======

__global__ __launch_bounds__(256) void prep_hist(
    const void* __restrict__ nodes,
    const void* __restrict__ W0, const void* __restrict__ W1, const void* __restrict__ W2,
    int* __restrict__ flag_out,
    unsigned short* __restrict__ nh, unsigned short* __restrict__ nl,
    unsigned short* __restrict__ T0, unsigned short* __restrict__ T1,
    unsigned short* __restrict__ T2,
    const int* __restrict__ recv, int* __restrict__ cnt, long nelem, int E) {
    __shared__ int sflag;
    if (threadIdx.x == 0) sflag = 0;
    __syncthreads();
    {
        const uint4* pw = (const uint4*)nodes;
        int hits = 0;
        for (int i = threadIdx.x; i < 2048; i += 256) {
            uint4 u = pw[i];
            unsigned int w[4] = {u.x, u.y, u.z, u.w};
            #pragma unroll
            for (int j = 0; j < 4; j++) {
                if ((w[j] & 0x7F80u) == 0x7F80u) hits++;
                if (((w[j] >> 16) & 0x7F80u) == 0x7F80u) hits++;
            }
        }
        if (__ballot(hits != 0)) { if ((threadIdx.x & 63) == 0) sflag = 1; }
    }
    __syncthreads();
    const bool f32 = (sflag != 0);
    if (blockIdx.x == 0 && threadIdx.x == 0) *flag_out = f32 ? 100 : 0;

    int g = blockIdx.x * 256 + threadIdx.x;
    int stride = gridDim.x * 256;
    if (f32) {
        for (long i = (long)g * 4; i < nelem; i += (long)stride * 4) {
            f32x4 v = *(const f32x4*)((const float*)nodes + i);
            s16x4 vh, vl;
            #pragma unroll
            for (int j = 0; j < 4; j++) {
                unsigned short hb = f2b(v[j]);
                vh[j] = (short)hb;
                vl[j] = (short)f2b(v[j] - b2f(hb));
            }
            *(s16x4*)(nh + i) = vh;
            *(s16x4*)(nl + i) = vl;
        }
    }
    for (int i = g; i < 40960; i += stride) {
        if (i < 8192) {
            int k = i >> 6, n = i & 63;
            T0[n * 128 + k] = f32 ? f2b(((const float*)W0)[i])
                                  : ((const unsigned short*)W0)[i];
        } else {
            const void* W; unsigned short* T; int o;
            if (i < 24576) { W = W1; T = T1; o = i - 8192; }
            else           { W = W2; T = T2; o = i - 24576; }
            int k = o >> 6, n = o & 63;
            float w = ldw(W, o, f32);
            T[n * 256 + k] = f32 ? f2b(w) : (unsigned short)f2h(w);
        }
    }
    for (int i = g; i < E; i += stride) atomicAdd(&cnt[recv[i]], 1);
}

__global__ __launch_bounds__(1024) void scan_kernel(const int* __restrict__ cnt,
                                                    int* __restrict__ off,
                                                    int* __restrict__ cursor, int n,
                                                    int* __restrict__ ssorted, int E) {
    if (threadIdx.x < 64) ssorted[E + threadIdx.x] = 0;
    const int C = (n + 1023) >> 10;
    int tid = threadIdx.x;
    int base = tid * C;
    int v[32];
    int tot = 0;
    for (int j = 0; j < C; j++) {
        int idx = base + j;
        int x = (idx < n) ? cnt[idx] : 0;
        v[j] = tot;
        tot += x;
    }
    int lane = tid & 63, w = tid >> 6;
    int incl = tot;
    #pragma unroll
    for (int s = 1; s < 64; s <<= 1) {
        int t = __shfl_up(incl, s, 64);
        if (lane >= s) incl += t;
    }
    __shared__ int wsum[16];
    __shared__ int woff[16];
    if (lane == 63) wsum[w] = incl;
    __syncthreads();
    if (tid < 16) {
        int s = 0;
        for (int i = 0; i < tid; i++) s += wsum[i];
        woff[tid] = s;
    }
    __syncthreads();
    int toff = woff[w] + (incl - tot);
    for (int j = 0; j < C; j++) {
        int idx = base + j;
        if (idx < n) { off[idx] = toff + v[j]; cursor[idx] = toff + v[j]; }
    }
    if (tid == 1023) off[n] = toff + tot;
}

__global__ __launch_bounds__(256) void gemm0_scatter(
    const void* __restrict__ nodes,
    const unsigned short* __restrict__ nh, const unsigned short* __restrict__ nl,
    const unsigned short* __restrict__ Wt, const void* __restrict__ bq,
    const int* __restrict__ flag, _Float16* __restrict__ h, int M,
    const int* __restrict__ recv, const int* __restrict__ send,
    int* __restrict__ cursor, int* __restrict__ ssorted, int E, int gemmBlocks) {
    __shared__ __align__(16) unsigned short Ws[64 * 136];
    if ((int)blockIdx.x < gemmBlocks) {
        const bool f32 = (*flag >= 8);
        if (f32) gemm_phase<128, 2>(nh, nl, Wt, bq, true, h, M, Ws, gemmBlocks * 4);
        else     gemm_phase<128, 0>((const unsigned short*)nodes, nullptr, Wt, bq,
                                    false, h, M, Ws, gemmBlocks * 4);
    } else {
        int g = (blockIdx.x - gemmBlocks) * 256 + threadIdx.x;
        int stride = (gridDim.x - gemmBlocks) * 256;
        for (int i = g; i < E; i += stride) {
            int pos = atomicAdd(&cursor[recv[i]], 1);
            ssorted[pos] = send[i] * HID;
        }
    }
}

template <int K>
__global__ __launch_bounds__(256) void gemm_mfma(const unsigned short* __restrict__ Ah,
                                                 const unsigned short* __restrict__ Al,
                                                 const unsigned short* __restrict__ Wt,
                                                 const void* __restrict__ bq,
                                                 const int* __restrict__ flag,
                                                 _Float16* __restrict__ h, int M) {
    __shared__ __align__(16) unsigned short Ws[64 * (K + 8)];
    const bool f32 = (*flag >= 8);
    if (f32) gemm_phase<K, 2>(Ah, Al, Wt, bq, true, h, M, Ws, gridDim.x * 4);
    else     gemm_phase<K, 1>(Ah, nullptr, Wt, bq, false, h, M, Ws, gridDim.x * 4);
}

__global__ __launch_bounds__(256) void attn_kernel(
    const _Float16* __restrict__ h, const int* __restrict__ off,
    const int* __restrict__ ssorted,
    const void* __restrict__ Wl, const void* __restrict__ bl,
    const int* __restrict__ flag,
    unsigned short* __restrict__ xh, unsigned short* __restrict__ xl,
    void* __restrict__ out, int n, int last) {
    const bool f32 = (*flag >= 8);
    attn_phase(h, off, ssorted, Wl, bl, f32, xh, xl, out, n, last, gridDim.x * 4);
}

// =================== launch ===================

extern "C" void kernel_launch(void* const* d_in, const int* in_sizes, int n_in,
                              void* d_out, int out_size, void* d_ws, size_t ws_size,
                              hipStream_t stream) {
    const void* nodes    = d_in[0];
    const int* senders   = (const int*)d_in[1];
    const int* receivers = (const int*)d_in[2];
    const void* Wq0 = d_in[3];  const void* bq0 = d_in[4];
    const void* Wl0 = d_in[5];  const void* bl0 = d_in[6];
    const void* Wq1 = d_in[7];  const void* bq1 = d_in[8];
    const void* Wl1 = d_in[9];  const void* bl1 = d_in[10];
    const void* Wq2 = d_in[11]; const void* bq2 = d_in[12];
    const void* Wl2 = d_in[13]; const void* bl2 = d_in[14];

    int N = in_sizes[0] / 128;
    int E = in_sizes[1];

    char* p = (char*)d_ws;
    int* flag = (int*)p;            p += 64;
    _Float16* h = (_Float16*)p;     p += (size_t)N * 64 * 2;            // 3.2 MB (L2-fit)
    unsigned short* nh = (unsigned short*)p;  p += (size_t)N * 128 * 2; // f32 world only
    unsigned short* nl = (unsigned short*)p;  p += (size_t)N * 128 * 2;
    unsigned short* xh = (unsigned short*)p;  p += (size_t)N * 256 * 2;
    unsigned short* xl = (unsigned short*)p;  p += (size_t)N * 256 * 2; // f32 world only
    unsigned short* Wt0 = (unsigned short*)p; p += 128 * 64 * 2;
    unsigned short* Wt1 = (unsigned short*)p; p += 256 * 64 * 2;
    unsigned short* Wt2 = (unsigned short*)p; p += 256 * 64 * 2;
    int* off = (int*)p;             p += (((size_t)N + 1 + 63) / 64) * 64 * 4;
    int* cnt = (int*)p;             p += (((size_t)N + 63) / 64) * 64 * 4;
    int* cursor = (int*)p;          p += (((size_t)N + 63) / 64) * 64 * 4;
    int* ssorted = (int*)p;         p += ((size_t)E + 64) * 4;          // +64 pad
    int* bsum = (int*)p;            p += 1032 * 4;

    // ---- try the cooperative mega-kernel (1 dispatch) ----
    int blocksPerCU = 0;
    if (hipOccupancyMaxActiveBlocksPerMultiprocessor(&blocksPerCU,
            reinterpret_cast<const void*>(&mega), 256, 0) != hipSuccess || blocksPerCU <= 0)
        blocksPerCU = 4;   // resource math: 34.9KB LDS, launch_bounds(256,4)
    long nbl = (long)blocksPerCU * 256;              // 256 CUs (gfx950)
    int nb = (int)(nbl > 1024 ? 1024 : nbl);
    if (nb >= 256) {
        void* out = d_out;
        void* kargs[] = {
            (void*)&nodes, (void*)&senders, (void*)&receivers,
            (void*)&Wq0, (void*)&bq0, (void*)&Wl0, (void*)&bl0,
            (void*)&Wq1, (void*)&bq1, (void*)&Wl1, (void*)&bl1,
            (void*)&Wq2, (void*)&bq2, (void*)&Wl2, (void*)&bl2,
            (void*)&h, (void*)&nh, (void*)&nl, (void*)&xh, (void*)&xl,
            (void*)&Wt0, (void*)&Wt1, (void*)&Wt2,
            (void*)&off, (void*)&cnt, (void*)&cursor, (void*)&ssorted, (void*)&bsum,
            (void*)&out, (void*)&N, (void*)&E
        };
        if (hipLaunchCooperativeKernel(reinterpret_cast<const void*>(&mega),
                dim3(nb), dim3(256), kargs, 0, stream) == hipSuccess)
            return;
    }

    // ---- fallback: R14 multi-kernel path ----
    hipMemsetAsync(cnt, 0, (size_t)N * sizeof(int), stream);
    long nelem = (long)N * 128;
    prep_hist<<<1024, 256, 0, stream>>>(nodes, Wq0, Wq1, Wq2, flag, nh, nl,
                                        Wt0, Wt1, Wt2, receivers, cnt, nelem, E);
    scan_kernel<<<1, 1024, 0, stream>>>(cnt, off, cursor, N, ssorted, E);

    int attnGrid = (N + 3) / 4;
    int tiles = (N + 15) / 16;
    int gemmGrid = (tiles + 3) / 4;

    gemm0_scatter<<<gemmGrid * 2, 256, 0, stream>>>(nodes, nh, nl, Wt0, bq0, flag, h, N,
                                                    receivers, senders, cursor, ssorted,
                                                    E, gemmGrid);
    attn_kernel<<<attnGrid, 256, 0, stream>>>(h, off, ssorted, Wl0, bl0, flag,
                                              xh, xl, nullptr, N, 0);
    gemm_mfma<256><<<gemmGrid, 256, 0, stream>>>(xh, xl, Wt1, bq1, flag, h, N);
    attn_kernel<<<attnGrid, 256, 0, stream>>>(h, off, ssorted, Wl1, bl1, flag,
                                              xh, xl, nullptr, N, 0);
    gemm_mfma<256><<<gemmGrid, 256, 0, stream>>>(xh, xl, Wt2, bq2, flag, h, N);
    attn_kernel<<<attnGrid, 256, 0, stream>>>(h, off, ssorted, Wl2, bl2, flag,
                                              nullptr, nullptr, d_out, N, 1);
}

// Round 17
// 275.585 us; speedup vs baseline: 3.2138x; 3.2138x over previous
//
#include <hip/hip_runtime.h>
#include <hip/hip_bf16.h>

#define HID 64
#define HEADS 4

typedef short s16x8 __attribute__((ext_vector_type(8)));   // 8 bf16/f16 (4 VGPRs)
typedef short s16x4 __attribute__((ext_vector_type(4)));
typedef float f32x4 __attribute__((ext_vector_type(4)));
typedef float f32x2 __attribute__((ext_vector_type(2)));

// flag convention: *flag >= 8  =>  float inputs are fp32; else bf16.
__device__ __forceinline__ float ldw(const void* p, long i, bool f32) {
    return f32 ? ((const float*)p)[i] : (float)((const __hip_bfloat16*)p)[i];
}

__device__ __forceinline__ unsigned short f2b(float f) {   // fp32 -> bf16 bits (RNE, finite)
    unsigned int u = __builtin_bit_cast(unsigned int, f);
    u += 0x7FFF + ((u >> 16) & 1);
    return (unsigned short)(u >> 16);
}
__device__ __forceinline__ float b2f(unsigned short s) {
    unsigned int u = ((unsigned int)s) << 16;
    return __builtin_bit_cast(float, u);
}
__device__ __forceinline__ short f2h(float f) {            // fp32 -> fp16 bits
    return __builtin_bit_cast(short, (_Float16)f);
}

#if __has_builtin(__builtin_amdgcn_exp2f)
#define EXP2(x) __builtin_amdgcn_exp2f(x)     // single v_exp_f32
#else
#define EXP2(x) exp2f(x)
#endif
#if __has_builtin(__builtin_amdgcn_rcpf)
#define RCP(x) __builtin_amdgcn_rcpf(x)
#else
#define RCP(x) (1.0f / (x))
#endif

// ---------------- fused prep: SELF-DETECT + (f32-only A planes) + W^T + histogram -
__global__ __launch_bounds__(256) void prep_hist(
    const void* __restrict__ nodes,
    const void* __restrict__ W0, const void* __restrict__ W1, const void* __restrict__ W2,
    int* __restrict__ flag_out,
    unsigned short* __restrict__ nh, unsigned short* __restrict__ nl,
    unsigned short* __restrict__ T0, unsigned short* __restrict__ T1,
    unsigned short* __restrict__ T2,
    const int* __restrict__ recv, int* __restrict__ cnt, long nelem, int E) {
    __shared__ int sflag;
    if (threadIdx.x == 0) sflag = 0;
    __syncthreads();
    {
        const uint4* pw = (const uint4*)nodes;       // 2048 uint4 = 16384 ushorts
        int hits = 0;
        for (int i = threadIdx.x; i < 2048; i += 256) {
            uint4 u = pw[i];
            unsigned int w[4] = {u.x, u.y, u.z, u.w};
            #pragma unroll
            for (int j = 0; j < 4; j++) {
                if ((w[j] & 0x7F80u) == 0x7F80u) hits++;               // low half
                if (((w[j] >> 16) & 0x7F80u) == 0x7F80u) hits++;       // high half
            }
        }
        if (__ballot(hits != 0)) { if ((threadIdx.x & 63) == 0) sflag = 1; }
    }
    __syncthreads();
    const bool f32 = (sflag != 0);
    if (blockIdx.x == 0 && threadIdx.x == 0) *flag_out = f32 ? 100 : 0;

    int g = blockIdx.x * 256 + threadIdx.x;
    int stride = gridDim.x * 256;

    // f32 world ONLY: A -> bf16 hi/lo planes (bf16 world reads nodes directly)
    if (f32) {
        for (long i = (long)g * 4; i < nelem; i += (long)stride * 4) {
            f32x4 v = *(const f32x4*)((const float*)nodes + i);
            s16x4 vh, vl;
            #pragma unroll
            for (int j = 0; j < 4; j++) {
                unsigned short hb = f2b(v[j]);
                vh[j] = (short)hb;
                vl[j] = (short)f2b(v[j] - b2f(hb));
            }
            *(s16x4*)(nh + i) = vh;
            *(s16x4*)(nl + i) = vl;
        }
    }
    // W [K,64] -> W^T [64,K]
    for (int i = g; i < 40960; i += stride) {
        int k, n;
        if (i < 8192) {                                  // T0: layer-0 weights
            k = i >> 6; n = i & 63;
            T0[n * 128 + k] = f32 ? f2b(((const float*)W0)[i])
                                  : ((const unsigned short*)W0)[i];   // raw bf16 copy
        } else {
            const void* W; unsigned short* T; int o;
            if (i < 24576) { W = W1; T = T1; o = i - 8192; }
            else           { W = W2; T = T2; o = i - 24576; }
            k = o >> 6; n = o & 63;
            float w = ldw(W, o, f32);
            T[n * 256 + k] = f32 ? f2b(w) : (unsigned short)f2h(w);
        }
    }
    // receiver histogram
    for (int i = g; i < E; i += stride) atomicAdd(&cnt[recv[i]], 1);
}

// ---------------- single-block scan (exclusive prefix of cnt) + ssorted pad ------
__global__ __launch_bounds__(1024) void scan_kernel(const int* __restrict__ cnt,
                                                    int* __restrict__ off,
                                                    int* __restrict__ cursor, int n,
                                                    int* __restrict__ ssorted, int E) {
    if (threadIdx.x < 64) ssorted[E + threadIdx.x] = 0;    // pad for uncond. loads
    const int C = (n + 1023) >> 10;          // assume <= 32
    int tid = threadIdx.x;
    int base = tid * C;
    int v[32];
    int tot = 0;
    for (int j = 0; j < C; j++) {
        int idx = base + j;
        int x = (idx < n) ? cnt[idx] : 0;
        v[j] = tot;
        tot += x;
    }
    int lane = tid & 63, w = tid >> 6;
    int incl = tot;
    #pragma unroll
    for (int s = 1; s < 64; s <<= 1) {
        int t = __shfl_up(incl, s, 64);
        if (lane >= s) incl += t;
    }
    __shared__ int wsum[16];
    __shared__ int woff[16];
    if (lane == 63) wsum[w] = incl;
    __syncthreads();
    if (tid < 16) {
        int s = 0;
        for (int i = 0; i < tid; i++) s += wsum[i];
        woff[tid] = s;
    }
    __syncthreads();
    int toff = woff[w] + (incl - tot);
    for (int j = 0; j < C; j++) {
        int idx = base + j;
        if (idx < n) { off[idx] = toff + v[j]; cursor[idx] = toff + v[j]; }
    }
    if (tid == 1023) off[n] = toff + tot;
}

// ---------------- MFMA GEMM body: h = A @ W + b ----------------
// W^T staged in LDS per block (R14 win); +8 fp16 row pad -> 2-way conflicts only.
// AMODE 0: A bf16 single plane (layer-0 bf16 world, exact).
// AMODE 1: A fp16 single plane (layers 1-2 bf16 world).
// AMODE 2: A bf16 hi/lo planes (f32 world, fp32-grade).
template <int K, int AMODE>
__device__ __forceinline__ void gemm_body(const unsigned short* __restrict__ Ah,
                                          const unsigned short* __restrict__ Al,
                                          const unsigned short* __restrict__ Wt,
                                          const void* __restrict__ bq,
                                          bool f32,
                                          _Float16* __restrict__ h, int M, int blockId) {
    constexpr int KP = K + 8;
    __shared__ __align__(16) unsigned short Ws[64 * KP];
    int tid = threadIdx.x;
    #pragma unroll
    for (int it = 0; it < (64 * K) / 2048; it++) {       // coalesced 16B staging
        int i = it * 2048 + tid * 8;
        int row = i / K, col = i % K;
        *(s16x8*)&Ws[row * KP + col] = *(const s16x8*)(Wt + i);
    }
    __syncthreads();

    int lane = tid & 63, wv = tid >> 6;
    int m16 = lane & 15, quad = lane >> 4;

    int tiles = (M + 15) >> 4;
    int tile = blockId * 4 + wv;
    if (tile >= tiles) return;

    float bias[4];
    #pragma unroll
    for (int t = 0; t < 4; t++) bias[t] = ldw(bq, 16 * t + m16, f32);

    int m0 = tile << 4;
    int row = m0 + m16;
    bool rv = row < M;
    long abase = (long)row * K;
    f32x4 acc[4] = {{0.f,0.f,0.f,0.f},{0.f,0.f,0.f,0.f},{0.f,0.f,0.f,0.f},{0.f,0.f,0.f,0.f}};

    #pragma unroll
    for (int ks = 0; ks < K / 32; ks++) {
        int kb = ks * 32 + quad * 8;
        s16x8 b[4];
        #pragma unroll
        for (int t = 0; t < 4; t++)
            b[t] = *(const s16x8*)&Ws[(16 * t + m16) * KP + kb];     // LDS, 2-way max
        s16x8 ah = rv ? *(const s16x8*)(Ah + abase + kb) : (s16x8){0,0,0,0,0,0,0,0};
        if (AMODE == 0) {
            #pragma unroll
            for (int t = 0; t < 4; t++)
                acc[t] = __builtin_amdgcn_mfma_f32_16x16x32_bf16(ah, b[t], acc[t], 0, 0, 0);
        } else if (AMODE == 1) {
            #pragma unroll
            for (int t = 0; t < 4; t++)
                acc[t] = __builtin_amdgcn_mfma_f32_16x16x32_f16(ah, b[t], acc[t], 0, 0, 0);
        } else {
            #pragma unroll
            for (int t = 0; t < 4; t++)
                acc[t] = __builtin_amdgcn_mfma_f32_16x16x32_bf16(ah, b[t], acc[t], 0, 0, 0);
            s16x8 al = rv ? *(const s16x8*)(Al + abase + kb) : (s16x8){0,0,0,0,0,0,0,0};
            #pragma unroll
            for (int t = 0; t < 4; t++)
                acc[t] = __builtin_amdgcn_mfma_f32_16x16x32_bf16(al, b[t], acc[t], 0, 0, 0);
        }
    }

    #pragma unroll
    for (int t = 0; t < 4; t++) {
        #pragma unroll
        for (int r = 0; r < 4; r++) {
            int orow = m0 + quad * 4 + r;        // C/D: col=lane&15, row=quad*4+reg
            if (orow < M) h[(long)orow * 64 + 16 * t + m16] = (_Float16)(acc[t][r] + bias[t]);
        }
    }
}

// layers 1-2: A = x (fp16 plane in bf16 world; hi/lo in f32 world)
template <int K>
__global__ __launch_bounds__(256) void gemm_mfma(const unsigned short* __restrict__ Ah,
                                                 const unsigned short* __restrict__ Al,
                                                 const unsigned short* __restrict__ Wt,
                                                 const void* __restrict__ bq,
                                                 const int* __restrict__ flag,
                                                 _Float16* __restrict__ h, int M) {
    const bool f32 = (*flag >= 8);
    if (f32) gemm_body<K, 2>(Ah, Al, Wt, bq, true, h, M, blockIdx.x);
    else     gemm_body<K, 1>(Ah, nullptr, Wt, bq, false, h, M, blockIdx.x);
}

// ---------------- fused: layer-0 GEMM + edge scatter (pre-scaled sender ids) -----
__global__ __launch_bounds__(256) void gemm0_scatter(
    const void* __restrict__ nodes,
    const unsigned short* __restrict__ nh, const unsigned short* __restrict__ nl,
    const unsigned short* __restrict__ Wt, const void* __restrict__ bq,
    const int* __restrict__ flag, _Float16* __restrict__ h, int M,
    const int* __restrict__ recv, const int* __restrict__ send,
    int* __restrict__ cursor, int* __restrict__ ssorted, int E, int gemmBlocks) {
    if ((int)blockIdx.x < gemmBlocks) {
        const bool f32 = (*flag >= 8);
        if (f32) gemm_body<128, 2>(nh, nl, Wt, bq, true, h, M, blockIdx.x);
        else     gemm_body<128, 0>((const unsigned short*)nodes, nullptr, Wt, bq,
                                   false, h, M, blockIdx.x);
    } else {
        int g = (blockIdx.x - gemmBlocks) * 256 + threadIdx.x;
        int stride = (gridDim.x - gemmBlocks) * 256;
        for (int i = g; i < E; i += stride) {
            int pos = atomicAdd(&cursor[recv[i]], 1);
            ssorted[pos] = send[i] * HID;        // pre-scaled element index
        }
    }
}

// ---------------- Attention: segment softmax (no-max, exp2-folded) + aggregate ----
// One wave per receiver; lane = hidden dim. fp16 h rows (L2-resident). Raw-load
// depth-8 pipeline (cvt at USE time -- R9 lesson). ssorted pre-scaled + padded.
// R12 lesson: no in-wave GEMM fusion. R15 lesson: no receiver batching (TLP wins).
// R16 lesson: no cooperative mega-kernel (grid.sync flushes per-XCD L2).
__global__ __launch_bounds__(256) void attn_kernel(
    const _Float16* __restrict__ h, const int* __restrict__ off,
    const int* __restrict__ ssorted,
    const void* __restrict__ Wl, const void* __restrict__ bl,
    const int* __restrict__ flag,
    unsigned short* __restrict__ xh, unsigned short* __restrict__ xl,
    void* __restrict__ out, int n, int last) {
    const bool f32 = (*flag >= 8);
    int lane = threadIdx.x & 63;
    int r = __builtin_amdgcn_readfirstlane(blockIdx.x * 4 + (threadIdx.x >> 6));
    if (r >= n) return;

    int start = off[r], end = off[r + 1];    // scalar (r wave-uniform) -- load FIRST
    int sv = ssorted[start + lane];          // unconditional (pad makes it safe)

    const float LOG2E = 1.44269504f;
    float hr = (float)h[(long)r * HID + lane];
    f32x2 w0p[2], cp[2];
    #pragma unroll
    for (int q = 0; q < 2; q++) {
        #pragma unroll
        for (int c = 0; c < 2; c++) {
            int k = 2 * q + c;
            float w0 = ldw(Wl, k, f32) * LOG2E;
            float w1 = ldw(Wl, HEADS + k, f32) * LOG2E;
            float bb = ldw(bl, k, f32) * LOG2E;
            w0p[q][c] = w0;
            cp[q][c] = fmaf(hr, w1, bb);     // receiver part: loop-invariant
        }
    }

    f32x2 lp[2] = {{0.f, 0.f}, {0.f, 0.f}};
    f32x2 ap[2] = {{0.f, 0.f}, {0.f, 0.f}};
    const _Float16* hbp = h + lane;          // gather base for this lane's dim

    for (int base = start; base < end; base += 64) {
        if (base != start) sv = ssorted[base + lane];      // first chunk preloaded
        int cnt = min(64, end - base);

        // RAW load, pre-scaled index, no cvt attached (pipeline-safe)
        #define LD(j) hbp[(long)__builtin_amdgcn_readlane(sv, (j))]
        #define STEP(hc) {                                                     \
            float _h = (float)(hc);          /* cvt at USE time */             \
            _Pragma("unroll")                                                  \
            for (int q = 0; q < 2; q++) {                                      \
                f32x2 t = w0p[q] * _h + cp[q];                                 \
                f32x2 u = t * 0.2f;                                            \
                t.x = fmaxf(t.x, u.x); t.y = fmaxf(t.y, u.y);                  \
                f32x2 pe; pe.x = EXP2(t.x); pe.y = EXP2(t.y);                  \
                lp[q] += pe;                                                   \
                ap[q] += pe * _h;                                              \
            } }

        _Float16 q0 = LD(0), q1 = LD(1), q2 = LD(2), q3 = LD(3);   // depth-8 prologue
        _Float16 q4 = LD(4), q5 = LD(5), q6 = LD(6), q7 = LD(7);   // (pad-safe)
        int j = 0;
        for (; j + 8 <= cnt; j += 8) {
            _Float16 a0 = q0, a1 = q1, a2 = q2, a3 = q3;
            _Float16 a4 = q4, a5 = q5, a6 = q6, a7 = q7;
            if (j + 8 < 64) {                // refill unconditionally within chunk
                q0 = LD(j +  8); q1 = LD(j +  9); q2 = LD(j + 10); q3 = LD(j + 11);
                q4 = LD(j + 12); q5 = LD(j + 13); q6 = LD(j + 14); q7 = LD(j + 15);
            }
            STEP(a0); STEP(a1); STEP(a2); STEP(a3);
            STEP(a4); STEP(a5); STEP(a6); STEP(a7);
        }
        int remn = cnt - j;                  // 0..7 tail, registers already loaded
        if (remn > 0) STEP(q0);
        if (remn > 1) STEP(q1);
        if (remn > 2) STEP(q2);
        if (remn > 3) STEP(q3);
        if (remn > 4) STEP(q4);
        if (remn > 5) STEP(q5);
        if (remn > 6) STEP(q6);
        #undef LD
        #undef STEP
    }

    bool has = (end > start);
    if (!last) {
        float v[4];
        #pragma unroll
        for (int k = 0; k < HEADS; k++) {
            float a = has ? ap[k >> 1][k & 1] * RCP(lp[k >> 1][k & 1]) : 0.f;
            v[k] = (a > 0.f) ? a : (__expf(a) - 1.f);    // elu
        }
        long o = (long)r * (HID * HEADS) + lane * HEADS; // reshape: d*HEADS+k
        if (!f32) {
            s16x4 vf;                                    // single fp16 plane
            #pragma unroll
            for (int k = 0; k < HEADS; k++) vf[k] = f2h(v[k]);
            *(s16x4*)(xh + o) = vf;
        } else {
            s16x4 vh, vlo;                               // hi/lo bf16 planes
            #pragma unroll
            for (int k = 0; k < HEADS; k++) {
                unsigned short hbk = f2b(v[k]);
                vh[k] = (short)hbk;
                vlo[k] = (short)f2b(v[k] - b2f(hbk));
            }
            *(s16x4*)(xh + o) = vh;
            *(s16x4*)(xl + o) = vlo;
        }
    } else {
        float s = 0.f;
        #pragma unroll
        for (int k = 0; k < HEADS; k++)
            s += has ? ap[k >> 1][k & 1] * RCP(lp[k >> 1][k & 1]) : 0.f;
        float a = s * 0.25f;                             // mean over heads
        a = (a > 0.f) ? a : (__expf(a) - 1.f);           // elu
        if (f32) ((float*)out)[(long)r * HID + lane] = a;
        else     ((__hip_bfloat16*)out)[(long)r * HID + lane] = (__hip_bfloat16)a;
    }
}

// ---------------- launch ----------------

extern "C" void kernel_launch(void* const* d_in, const int* in_sizes, int n_in,
                              void* d_out, int out_size, void* d_ws, size_t ws_size,
                              hipStream_t stream) {
    const void* nodes    = d_in[0];
    const int* senders   = (const int*)d_in[1];
    const int* receivers = (const int*)d_in[2];
    const void* Wq0 = d_in[3];  const void* bq0 = d_in[4];
    const void* Wl0 = d_in[5];  const void* bl0 = d_in[6];
    const void* Wq1 = d_in[7];  const void* bq1 = d_in[8];
    const void* Wl1 = d_in[9];  const void* bl1 = d_in[10];
    const void* Wq2 = d_in[11]; const void* bq2 = d_in[12];
    const void* Wl2 = d_in[13]; const void* bl2 = d_in[14];

    int N = in_sizes[0] / 128;
    int E = in_sizes[1];

    char* p = (char*)d_ws;
    int* flag = (int*)p;            p += 64;
    _Float16* h = (_Float16*)p;     p += (size_t)N * 64 * 2;            // 3.2 MB (L2-fit)
    unsigned short* nh = (unsigned short*)p;  p += (size_t)N * 128 * 2; // f32 world only
    unsigned short* nl = (unsigned short*)p;  p += (size_t)N * 128 * 2;
    unsigned short* xh = (unsigned short*)p;  p += (size_t)N * 256 * 2; // 12.8 MB
    unsigned short* xl = (unsigned short*)p;  p += (size_t)N * 256 * 2; // f32 world only
    unsigned short* Wt0 = (unsigned short*)p; p += 128 * 64 * 2;
    unsigned short* Wt1 = (unsigned short*)p; p += 256 * 64 * 2;
    unsigned short* Wt2 = (unsigned short*)p; p += 256 * 64 * 2;
    int* off = (int*)p;             p += (((size_t)N + 1 + 63) / 64) * 64 * 4;
    int* cnt = (int*)p;             p += (((size_t)N + 63) / 64) * 64 * 4;
    int* cursor = (int*)p;          p += (((size_t)N + 63) / 64) * 64 * 4;
    int* ssorted = (int*)p;         p += ((size_t)E + 64) * 4;          // +64 pad

    hipMemsetAsync(cnt, 0, (size_t)N * sizeof(int), stream);

    long nelem = (long)N * 128;
    prep_hist<<<1024, 256, 0, stream>>>(nodes, Wq0, Wq1, Wq2, flag, nh, nl,
                                        Wt0, Wt1, Wt2, receivers, cnt, nelem, E);
    scan_kernel<<<1, 1024, 0, stream>>>(cnt, off, cursor, N, ssorted, E);

    int attnGrid = (N + 3) / 4;
    int tiles = (N + 15) / 16;
    int gemmGrid = (tiles + 3) / 4;

    // layer-0 GEMM (direct bf16 nodes, LDS-staged W) fused with edge scatter
    gemm0_scatter<<<gemmGrid * 2, 256, 0, stream>>>(nodes, nh, nl, Wt0, bq0, flag, h, N,
                                                    receivers, senders, cursor, ssorted,
                                                    E, gemmGrid);
    attn_kernel<<<attnGrid, 256, 0, stream>>>(h, off, ssorted, Wl0, bl0, flag,
                                              xh, xl, nullptr, N, 0);
    // layer 1
    gemm_mfma<256><<<gemmGrid, 256, 0, stream>>>(xh, xl, Wt1, bq1, flag, h, N);
    attn_kernel<<<attnGrid, 256, 0, stream>>>(h, off, ssorted, Wl1, bl1, flag,
                                              xh, xl, nullptr, N, 0);
    // layer 2 (last: mean over heads + elu)
    gemm_mfma<256><<<gemmGrid, 256, 0, stream>>>(xh, xl, Wt2, bq2, flag, h, N);
    attn_kernel<<<attnGrid, 256, 0, stream>>>(h, off, ssorted, Wl2, bl2, flag,
                                              nullptr, nullptr, d_out, N, 1);
}